// Round 1
// baseline (73.367 us; speedup 1.0000x reference)
//
#include <hip/hip_runtime.h>
#include <math.h>

// Problem constants (from reference)
#define N_PRED 1000
#define M_BOX  2000
#define K_PASS 10
#define C_CLS  80
#define IOU_THR 0.5f
#define EPS_IOU 1e-7f

// One block per pred n; one wave (64 lanes) per dropout pass k.
// blockDim = K_PASS * 64 = 640.
__global__ __launch_bounds__(K_PASS * 64)
void ue_cls_kernel(const float* __restrict__ pred,    // [N,6]
                   const float* __restrict__ dpreds,  // [K,M,6]
                   const float* __restrict__ dconfs,  // [K,M,C]
                   float* __restrict__ out)           // [N]
{
    const int n    = blockIdx.x;
    const int wave = threadIdx.x >> 6;   // == k
    const int lane = threadIdx.x & 63;
    const int k    = wave;

    __shared__ float s_u[K_PASS];
    __shared__ float s_m[K_PASS];

    // pred box n (broadcast load; same address across lanes)
    const float px1 = pred[n * 6 + 0];
    const float py1 = pred[n * 6 + 1];
    const float px2 = pred[n * 6 + 2];
    const float py2 = pred[n * 6 + 3];
    const float area1 = (px2 - px1) * (py2 - py1);

    // first-match scan over M boxes, 64 at a time, wave-uniform break
    const long baseRow = (long)k * M_BOX;
    const float2* dp2 = (const float2*)dpreds;  // row stride 6 floats = 3 float2s, 8B-aligned
    int first = -1;
    for (int c0 = 0; c0 < M_BOX; c0 += 64) {
        const int m = c0 + lane;
        bool hit = false;
        if (m < M_BOX) {
            const long i2 = (baseRow + m) * 3;
            const float2 a = dp2[i2];
            const float2 b = dp2[i2 + 1];
            const float bx1 = a.x, by1 = a.y, bx2 = b.x, by2 = b.y;
            const float ix1 = fmaxf(px1, bx1);
            const float iy1 = fmaxf(py1, by1);
            const float ix2 = fminf(px2, bx2);
            const float iy2 = fminf(py2, by2);
            const float inter = fmaxf(ix2 - ix1, 0.0f) * fmaxf(iy2 - iy1, 0.0f);
            const float area2 = (bx2 - bx1) * (by2 - by1);
            const float iou = inter / (area1 + area2 - inter + EPS_IOU);
            hit = iou > IOU_THR;
        }
        const unsigned long long bal = __ballot(hit);
        if (bal) { first = c0 + __builtin_ctzll(bal); break; }
    }

    float u = 0.0f, matched = 0.0f;
    if (first >= 0) {
        matched = 1.0f;
        const float* row = dconfs + (baseRow + first) * C_CLS;
        float local = 0.0f;
        {
            const float p = row[lane];
            local -= p * logf(p);
        }
        if (lane < C_CLS - 64) {
            const float q = row[64 + lane];
            local -= q * logf(q);
        }
        // 64-lane butterfly reduce
        #pragma unroll
        for (int off = 32; off > 0; off >>= 1)
            local += __shfl_xor(local, off, 64);
        const float inv_n  = 1.0f / (float)C_CLS;
        const float max_en = -(float)C_CLS * (inv_n * logf(inv_n));  // == log(C), same expr as ref
        u = 1.0f - local / max_en;
    }

    if (lane == 0) { s_u[k] = u * matched; s_m[k] = matched; }
    __syncthreads();

    if (threadIdx.x == 0) {
        float cnt = 0.0f, su = 0.0f;
        #pragma unroll
        for (int kk = 0; kk < K_PASS; ++kk) { cnt += s_m[kk]; su += s_u[kk]; }
        out[n] = (cnt > 0.0f) ? (su / fmaxf(cnt, 1.0f)) : __builtin_nanf("");
    }
}

extern "C" void kernel_launch(void* const* d_in, const int* in_sizes, int n_in,
                              void* d_out, int out_size, void* d_ws, size_t ws_size,
                              hipStream_t stream) {
    const float* pred   = (const float*)d_in[0];   // [N,6]
    const float* dpreds = (const float*)d_in[1];   // [K,M,6]
    const float* dconfs = (const float*)d_in[2];   // [K,M,C]
    float* out = (float*)d_out;                    // [N]

    ue_cls_kernel<<<dim3(N_PRED), dim3(K_PASS * 64), 0, stream>>>(pred, dpreds, dconfs, out);
}